// Round 15
// baseline (2378.494 us; speedup 1.0000x reference)
//
#include <hip/hip_runtime.h>
#include <math.h>

// FISTA, phase-split 4x, XCD-colocated, L3-atomic exchange — R32 (= R31
// resubmitted byte-identical: R14's "container failed twice" was an
// INFRASTRUCTURE error, not a kernel signal — no new asm/sync/launch
// surface exists in this kernel vs the clean-running R26. Mutating the
// kernel in response would confound the experiment).
// R30 post-mortem: two-chain interleave REFUTED (1661us): 2x VALU/block on
// half the CUs + 8 barriers; occupancy 13.6%. Reverted to R26 (955us).
// R26 budget re-derivation with m134 LDS costs: LDS pipe ~7,650 cyc/CU-iter
// (67%) > VALU 6,536 (57%) -> LDS pipe is the binding resource. Largest
// item: all 9 waves read the SAME 25 weight b128s (weights depend only on
// (tap,lane)) = 225 reads/iter, 25 unique -> 2,700 cyc/CU-iter of pure
// redundancy (35% of pipe).
// R31/R32 = R26 verbatim + ONE change: the 75 weight floats are loaded into
// registers ONCE pre-loop FROM LDS (f32x2 wp01[25] + float wp2[25], all
// compile-time indexed in the fully-unrolled tap loop).
//  - Unlike R19/R21/R24 (global-source hoists: scratch spill / global
//    remat, FETCH 5.4GB): here the source is LDS, so compiler-declined
//    residency degrades to an LDS re-read == exactly R26's current code.
//  - VGPR budget: 576thr -> 3 waves/SIMD -> 168 regs; peak live ~140-150.
//  - Verification signals: VGPR ~140-160 & WRITE flat = resident (win);
//    VGPR ~68-90 = remat (flat); WRITE >> 66.7MB = scratch (revert).
//
// Kept verbatim from R23-R26 (955us lineage): conv weights LDS layout
// [tap][lane][4]; pk_fma stage-1 (f32x2 a01[9] + a2[9]); compile-time
// column trim; DPP(2-stage)+stride-20 transpose reduce + ONE coalesced
// 27-lane atomic store; pre-gate stage-2 prefetch (y/ylast/Wct b128);
// prepass stores r = x - a; Wct stride-200; 4-sync centralized exchange
// (tid0 relaxed fetch_add + relaxed spin, target 4*(iter+1)).
// WAR audit: pre-pass(k) < end-barrier(k) < stage1(k+1) < add(k+1);
// spin(k+1) sees 4(k+2) => all blocks did pre-pass(k); only then
// stage1(k+2) rewrites buffer k&1.
//
// Phase decomposition (proven R2-R30): a[cell,co] = sum_{d(5x5),ci,p}
// y[cell+d,ci,p] W[d,ci,p,co]; block g sums its 16 phases -> partial a.
// Wave = output row; lane = (q=ci quadrant, p_local); q=3 lanes carry zero
// weights (y reads duplicate q=2: same-address broadcast, free).

#define ITERS 200
#define THREADS 576
// d_ws float offsets
#define WGOFF 0          // 19200: [g][t*3+co][lane], q=3 lanes zeroed
#define WCTOFF 19200     // 600: [c(stride 200)][ci*64][p]
#define APOFF 19800      // 2 * 64 * 4 * 243 = 124416 (double-buffered)
#define CNTOFF 144256    // int offsets: 64 images x 64-int padding
// LDS float offsets
#define LY 0             // y: 3888 = 243 idx3 x 16 p_local (16B-aligned)
#define LYL 3888         // y_last: 3888
#define LA 7776          // r-values: 243 (+1 pad)
#define LXS 8020         // x image slice: 243 (+1 pad)
#define LWG 8264         // conv weights: 25 taps x 64 lanes x 4 (co,pad)
#define LWCT 14664       // Wct: 600 [c*200+ci*64+p]
#define LT 15264         // transpose scratch: 9 waves x 27 rows x stride 20
#define SMEMF 20608      // 82,432 B (> 80 KB -> exactly 1 block/CU)

typedef float f32x2 __attribute__((ext_vector_type(2)));

template <int CTRL>
__device__ __forceinline__ float dpp_add(float x) {
  int moved = __builtin_amdgcn_update_dpp(0, __float_as_int(x), CTRL, 0xF, 0xF, true);
  return x + __int_as_float(moved);
}

// WG[((g*75 + t*3 + co))*64 + lane] = w_conv[8*th+ph][8*tw+pw][ci=q][co]
//   with lane=(q,pl), p = g*16+pl; q==3 -> 0 (dead quadrant).
// WCT2[c*200 + ci*64 + p] = (rh<5 && rw<5) ? w_ct[4-rh][4-rw][ci][c] : 0.
__global__ void k0_init(const float* __restrict__ w_conv,
                        const float* __restrict__ w_ct,
                        float* __restrict__ ws) {
  const int i = blockIdx.x * 256 + threadIdx.x;
  if (i < 19200) {
    const int lane = i & 63;
    const int rest = i >> 6;          // g*75 + t*3 + co
    const int g = rest / 75;
    const int tc = rest - 75 * g;
    const int t = tc / 3;
    const int co = tc - 3 * t;
    const int th = t / 5;
    const int tw = t - 5 * th;
    const int q = lane >> 4;
    const int pl = lane & 15;
    float v = 0.f;
    if (q < 3) {
      const int p = g * 16 + pl;
      const int ph = p >> 3;
      const int pw = p & 7;
      v = w_conv[(((8 * th + ph) * 40 + (8 * tw + pw)) * 3 + q) * 3 + co];
    }
    ws[WGOFF + i] = v;
  }
  if (i < 600) {
    const int c = i / 200;
    const int rem = i - 200 * c;
    float v = 0.f;
    if (rem < 192) {
      const int ci = rem >> 6;
      const int p = rem & 63;
      const int rh = p >> 3;
      const int rw = p & 7;
      if (rh < 5 && rw < 5) v = w_ct[(((4 - rh) * 5 + (4 - rw)) * 3 + ci) * 3 + c];
    }
    ws[WCTOFF + i] = v;
  }
  if (i < 4096) ((int*)ws)[CNTOFF + i] = 0;
}

__global__ __launch_bounds__(THREADS) void fista_split(
    float* __restrict__ ws,
    const float* __restrict__ x, const float* __restrict__ lam,
    const float* __restrict__ b_conv, const float* __restrict__ b_ct,
    float* __restrict__ out) {
  __shared__ __align__(16) float smem[SMEMF];
  const int tid = threadIdx.x;
  const int blk = blockIdx.x;
  const int n = blk & 63;         // image  (XCD colocation: n, n+64, n+128,
  const int g = blk >> 6;         //  n+192 share blk%8)
  const int lane = tid & 63;
  const int wid = tid >> 6;       // wave index (9 waves)
  const int q = lane >> 4;        // ci quadrant (3 = dead)
  const int pl = lane & 15;
  const int ylane = ((q < 3) ? q : 2) * 16 + pl;  // q=3 dupes q=2: broadcast
  // wave->row perm {0,4,2,3,8,5,6,7,1}: per-SIMD tap-row load balanced (10).
  const int oh = (wid == 0) ? 0 : (wid == 1) ? 4 : (wid == 4) ? 8
               : (wid == 8) ? 1 : wid;

  int* __restrict__ cnt = (int*)ws + CNTOFF + n * 64;
  const float lam_n = lam[n];
  const float bcv = b_conv[tid % 3];   // pre-pass bias (used when tid<243)
  const float bct0 = b_ct[0], bct1 = b_ct[1], bct2 = b_ct[2];

  // ---- stage LDS: zero all, scatter conv weights to [tap][lane][4],
  // copy Wct + x slice ----
  for (int i = tid; i < SMEMF; i += THREADS) smem[i] = 0.f;
  __syncthreads();
  for (int i = tid; i < 4800; i += THREADS) {
    const int lane_i = i & 63;
    const int tc = i >> 6;            // t*3 + co
    const int t_i = tc / 3;
    const int co_i = tc - 3 * t_i;
    smem[LWG + (t_i * 64 + lane_i) * 4 + co_i] = ws[WGOFF + g * 4800 + i];
  }
  for (int i = tid; i < 600; i += THREADS) smem[LWCT + i] = ws[WCTOFF + i];
  if (tid < 243) smem[LXS + tid] = x[n * 243 + tid];
  __syncthreads();

  // ---- R31: weights -> registers ONCE, from LDS (compile-time indexed).
  // If the compiler declines residency, remat = LDS re-read == R26. ----
  f32x2 wp01[25];
  float wp2[25];
#pragma unroll
  for (int t5 = 0; t5 < 25; ++t5) {
    const float4 wv = *(const float4*)&smem[LWG + (t5 * 64 + lane) * 4];
    wp01[t5].x = wv.x; wp01[t5].y = wv.y;
    wp2[t5] = wv.z;
  }

  // stage-2 ownership: thread t<486 owns elements e = 8t .. 8t+7
  const int idx3 = tid >> 1;
  const int cell = idx3 / 3;
  const int c = idx3 - 3 * cell;
  const int cb = 3 * cell;
  const int plb = (tid & 1) * 8;       // p_local base (0 or 8)
  const int pb = g * 16 + plb;         // global p base

  float t = 1.0f;
#pragma unroll 1
  for (int iter = 0; iter < ITERS; ++iter) {
    // ===== stage 1: partial a over this block's 16 phases; wave = oh ==========
    {
      f32x2 a01[9];                // [ow] = (co0, co1)
      float a2[9];                 // [ow] = co2
#pragma unroll
      for (int k = 0; k < 9; ++k) { a01[k].x = 0.f; a01[k].y = 0.f; a2[k] = 0.f; }

#pragma unroll
      for (int th = 0; th < 5; ++th) {
        const int r = oh + th - 2;          // input row
        if (r >= 0 && r <= 8) {
          f32x2 y2[9];                      // broadcast pairs {y,y}
#pragma unroll
          for (int wc = 0; wc < 9; ++wc) {
            const float yv = smem[LY + r * 432 + wc * 48 + ylane];
            y2[wc].x = yv; y2[wc].y = yv;
          }

#pragma unroll
          for (int tw = 0; tw < 5; ++tw) {
            const int t5 = th * 5 + tw;
            const f32x2 w01 = wp01[t5];
            const float w2s = wp2[t5];
#pragma unroll
            for (int ow = 0; ow < 9; ++ow) {
              const int col = ow + tw - 2;
              if (col >= 0 && col <= 8) {   // compile-time trim
                a01[ow] += y2[col] * w01;   // v_pk_fma_f32
                a2[ow]  += y2[col].x * w2s;
              }
            }
          }
        }
      }

      // ---- reduce (R23-proven): 2 DPP stages -> 4-lane sums; masked
      // transpose write (stride 20, conflict-free); lanes<27 final sum;
      // ONE coalesced 27-lane atomic store ----
      float s4[27];
#pragma unroll
      for (int k = 0; k < 27; ++k) {
        const int ow = k / 3, co = k - 3 * ow;      // compile-time
        const float av = (co == 0) ? a01[ow].x : (co == 1) ? a01[ow].y : a2[ow];
        const float s1 = dpp_add<0x111>(av);        // row_shr:1
        s4[k] = dpp_add<0x112>(s1);                 // row_shr:2 -> 4-group sum
      }
      {
        float* Tw = &smem[LT + wid * 540];
        if ((lane & 3) == 3) {
          const int m = lane >> 2;                  // 0..15
#pragma unroll
          for (int k = 0; k < 27; ++k) Tw[k * 20 + m] = s4[k];
        }
        asm volatile("s_waitcnt lgkmcnt(0)" ::: "memory");
        if (lane < 27) {
          const float4* Tr = (const float4*)&Tw[lane * 20];
          const float4 p0 = Tr[0];
          const float4 p1 = Tr[1];
          const float4 p2 = Tr[2];
          const float4 p3 = Tr[3];
          const float s01 = (p0.x + p0.y) + (p0.z + p0.w);
          const float s23 = (p1.x + p1.y) + (p1.z + p1.w);
          const float s45 = (p2.x + p2.y) + (p2.z + p2.w);
          const float s67 = (p3.x + p3.y) + (p3.z + p3.w);
          const float s = (s01 + s23) + (s45 + s67);
          float* ap = ws + APOFF + ((((iter & 1) * 64 + n) * 4 + g) * 243)
                      + oh * 27 + lane;
          __hip_atomic_store(ap, s, __ATOMIC_RELAXED, __HIP_MEMORY_SCOPE_AGENT);
        }
      }
    }

    // ===== pre-gate prefetch: stage-2 operands -> regs (latency hides
    // under drain + spin; thread-owned slots only) =====
    float4 py0 = {}, py1 = {}, pq0 = {}, pq1 = {};
    float4 w0a = {}, w0b = {}, w1a = {}, w1b = {}, w2a = {}, w2b = {};
    if (tid < 486) {
      float4* lyv  = (float4*)&smem[LY];
      float4* lylv = (float4*)&smem[LYL];
      py0 = lyv[2 * tid];  py1 = lyv[2 * tid + 1];
      pq0 = lylv[2 * tid]; pq1 = lylv[2 * tid + 1];
      w0a = *(const float4*)&smem[LWCT + c * 200 +   0 + pb];
      w0b = *(const float4*)&smem[LWCT + c * 200 +   4 + pb];
      w1a = *(const float4*)&smem[LWCT + c * 200 +  64 + pb];
      w1b = *(const float4*)&smem[LWCT + c * 200 +  68 + pb];
      w2a = *(const float4*)&smem[LWCT + c * 200 + 128 + pb];
      w2b = *(const float4*)&smem[LWCT + c * 200 + 132 + pb];
    }

    // ===== centralized barrier (proven): one spinner, rest at s_barrier =====
    __syncthreads();               // compiler drains vmcnt: Ap stores acked at L3
    if (tid == 0) {
      __hip_atomic_fetch_add(cnt, 1, __ATOMIC_RELAXED, __HIP_MEMORY_SCOPE_AGENT);
      const int target = 4 * (iter + 1);
      while (__hip_atomic_load(cnt, __ATOMIC_RELAXED, __HIP_MEMORY_SCOPE_AGENT)
             < target)
        __builtin_amdgcn_s_sleep(1);
    }
    __syncthreads();

    // ===== pre-pass: r = x - (sum_g Ap + b_conv) -> LDS =====
    if (tid < 243) {
      const float* ap = ws + APOFF + ((iter & 1) * 64 + n) * 972;
      const float a0 = __hip_atomic_load(ap + tid, __ATOMIC_RELAXED,
                                         __HIP_MEMORY_SCOPE_AGENT);
      const float a1 = __hip_atomic_load(ap + 243 + tid, __ATOMIC_RELAXED,
                                         __HIP_MEMORY_SCOPE_AGENT);
      const float a2v = __hip_atomic_load(ap + 486 + tid, __ATOMIC_RELAXED,
                                          __HIP_MEMORY_SCOPE_AGENT);
      const float a3 = __hip_atomic_load(ap + 729 + tid, __ATOMIC_RELAXED,
                                         __HIP_MEMORY_SCOPE_AGENT);
      smem[LA + tid] = smem[LXS + tid] - (a0 + a1 + a2v + a3 + bcv);
    }
    __syncthreads();

    const float tn = (1.0f + sqrtf(1.0f + 4.0f * t * t)) * 0.5f;
    const float beta = (t - 1.0f) / tn;    // beta_0 = 0
    t = tn;

    // ===== stage 2: 8 elements/thread, all operands prefetched; reads
    // only the 3 r-values from LDS =====
    const bool lastit = (iter == ITERS - 1);
    if (tid < 486) {
      const float r0  = smem[LA + cb + 0];
      const float r1  = smem[LA + cb + 1];
      const float r2v = smem[LA + cb + 2];
      const float bct = (c == 0) ? bct0 : ((c == 1) ? bct1 : bct2);

      const float wct0[8] = {w0a.x, w0a.y, w0a.z, w0a.w, w0b.x, w0b.y, w0b.z, w0b.w};
      const float wct1[8] = {w1a.x, w1a.y, w1a.z, w1a.w, w1b.x, w1b.y, w1b.z, w1b.w};
      const float wct2[8] = {w2a.x, w2a.y, w2a.z, w2a.w, w2b.x, w2b.y, w2b.z, w2b.w};
      const float yv[8]   = {py0.x, py0.y, py0.z, py0.w, py1.x, py1.y, py1.z, py1.w};
      float yn[8];
#pragma unroll
      for (int j = 0; j < 8; ++j) {
        const float re = bct + r0 * wct0[j] + r1 * wct1[j] + r2v * wct2[j];
        const float wvv = yv[j] - re;
        yn[j] = fmaxf(wvv - lam_n, 0.f) - fmaxf(-wvv - lam_n, 0.f);
      }

      float4* lyv  = (float4*)&smem[LY];
      float4* lylv = (float4*)&smem[LYL];
      if (!lastit) {
        const float ylv[8] = {pq0.x, pq0.y, pq0.z, pq0.w, pq1.x, pq1.y, pq1.z, pq1.w};
        float4 s0, s1, m0, m1;
        s0.x = yn[0]; s0.y = yn[1]; s0.z = yn[2]; s0.w = yn[3];
        s1.x = yn[4]; s1.y = yn[5]; s1.z = yn[6]; s1.w = yn[7];
        m0.x = yn[0] + beta * (yn[0] - ylv[0]);
        m0.y = yn[1] + beta * (yn[1] - ylv[1]);
        m0.z = yn[2] + beta * (yn[2] - ylv[2]);
        m0.w = yn[3] + beta * (yn[3] - ylv[3]);
        m1.x = yn[4] + beta * (yn[4] - ylv[4]);
        m1.y = yn[5] + beta * (yn[5] - ylv[5]);
        m1.z = yn[6] + beta * (yn[6] - ylv[6]);
        m1.w = yn[7] + beta * (yn[7] - ylv[7]);
        lylv[2 * tid] = s0; lylv[2 * tid + 1] = s1;
        lyv[2 * tid]  = m0; lyv[2 * tid + 1]  = m1;
      } else {
        const int part = pb >> 3;           // p>>3 constant over j
        const int qh = cell / 9;
        const int qw = cell - 9 * qh;
        const int ih = 8 * qh + part;
        float* op = out + ((n * 72 + ih) * 72 + 8 * qw) * 3 + c;
#pragma unroll
        for (int j = 0; j < 8; ++j) op[3 * j] = yn[j];
      }
    }
    __syncthreads();
  }
}

extern "C" void kernel_launch(void* const* d_in, const int* in_sizes, int n_in,
                              void* d_out, int out_size, void* d_ws, size_t ws_size,
                              hipStream_t stream) {
  const float* x      = (const float*)d_in[0];
  const float* lam    = (const float*)d_in[1];
  const float* w_conv = (const float*)d_in[2];
  const float* b_conv = (const float*)d_in[3];
  const float* w_ct   = (const float*)d_in[4];
  const float* b_ct   = (const float*)d_in[5];
  float* out = (float*)d_out;
  float* ws  = (float*)d_ws;  // needs ~594 KB

  hipLaunchKernelGGL(k0_init, dim3(80), dim3(256), 0, stream, w_conv, w_ct, ws);
  hipLaunchKernelGGL(fista_split, dim3(256), dim3(THREADS), 0, stream,
                     ws, x, lam, b_conv, b_ct, out);
}

// Round 16
// 934.992 us; speedup vs baseline: 2.5439x; 2.5439x over previous
//
#include <hip/hip_runtime.h>
#include <math.h>

// FISTA, phase-split 4x, XCD-colocated, L3-atomic exchange — R33.
// R31/R32 post-mortem (4th register-hoist failure, diagnosed): compiler
// occupancy heuristic caps VGPR at 84 (=512/6, targets 6 waves/SIMD) and
// SPILLS any larger persistent array to scratch (WRITE +43MB one-time
// spill, FETCH 26MB -> 2.58GB per-iter reloads). Conclusion 4-for-4: no
// persistent array > ~8 floats survives in registers. Weight re-reads
// from LDS are structural; LDS pipe (~7.6k cyc/CU-iter) is the floor.
// R33 = R26 (955us, best) + the ONE surviving register lever:
//   y_last -> yl[8] PERSISTENT REGISTERS (+8 VGPR, 68->~76 < 84 cap).
//   y_last is touched only by its owning stage-2 thread, so LDS was never
//   needed: saves 4 b128 LDS ops/thread/iter (~365 cyc/CU-iter on the
//   binding LDS pipe) + the ylast prefetch. LYL region deleted; LDS
//   padded to 82,432 B so 1 block/CU packing is preserved.
//   Bitwise-identical arithmetic (yl holds exactly the old LYL values;
//   init 0 == zeroed LDS; lastit path unchanged).
// Verification signals: VGPR 76-84 & FETCH ~26MB flat = win; FETCH
// explosion = spill (revert); absmax must stay exactly 128.
//
// Kept verbatim from R23-R26: conv weights in LDS [tap][lane][4] b128;
// pk_fma stage-1 (f32x2 a01[9] + a2[9]); compile-time column trim;
// DPP(2)+stride-20 transpose reduce + ONE coalesced 27-lane atomic store;
// pre-gate stage-2 prefetch (y/Wct b128); prepass stores r = x - a;
// Wct stride-200; 4-sync centralized exchange (tid0 relaxed fetch_add +
// relaxed spin, target 4*(iter+1)).
// WAR audit: pre-pass(k) < end-barrier(k) < stage1(k+1) < add(k+1);
// spin(k+1) sees 4(k+2) => all blocks did pre-pass(k); only then
// stage1(k+2) rewrites buffer k&1.
//
// Phase decomposition (proven R2-R32): a[cell,co] = sum_{d(5x5),ci,p}
// y[cell+d,ci,p] W[d,ci,p,co]; block g sums its 16 phases -> partial a.
// Wave = output row; lane = (q=ci quadrant, p_local); q=3 lanes carry zero
// weights (y reads duplicate q=2: same-address broadcast, free).

#define ITERS 200
#define THREADS 576
// d_ws float offsets
#define WGOFF 0          // 19200: [g][t*3+co][lane], q=3 lanes zeroed
#define WCTOFF 19200     // 600: [c(stride 200)][ci*64][p]
#define APOFF 19800      // 2 * 64 * 4 * 243 = 124416 (double-buffered)
#define CNTOFF 144256    // int offsets: 64 images x 64-int padding
// LDS float offsets
#define LY 0             // y: 3888 = 243 idx3 x 16 p_local (16B-aligned)
#define LA 3888          // r-values: 243 (+1 pad)
#define LXS 4132         // x image slice: 243 (+1 pad)
#define LWG 4376         // conv weights: 25 taps x 64 lanes x 4 (co,pad)
#define LWCT 10776       // Wct: 600 [c*200+ci*64+p]
#define LT 11376         // transpose scratch: 9 waves x 27 rows x stride 20
                         // (ends 16236)
#define SMEMF 20608      // 82,432 B PADDED (> 80 KB -> exactly 1 block/CU)

typedef float f32x2 __attribute__((ext_vector_type(2)));

template <int CTRL>
__device__ __forceinline__ float dpp_add(float x) {
  int moved = __builtin_amdgcn_update_dpp(0, __float_as_int(x), CTRL, 0xF, 0xF, true);
  return x + __int_as_float(moved);
}

// WG[((g*75 + t*3 + co))*64 + lane] = w_conv[8*th+ph][8*tw+pw][ci=q][co]
//   with lane=(q,pl), p = g*16+pl; q==3 -> 0 (dead quadrant).
// WCT2[c*200 + ci*64 + p] = (rh<5 && rw<5) ? w_ct[4-rh][4-rw][ci][c] : 0.
__global__ void k0_init(const float* __restrict__ w_conv,
                        const float* __restrict__ w_ct,
                        float* __restrict__ ws) {
  const int i = blockIdx.x * 256 + threadIdx.x;
  if (i < 19200) {
    const int lane = i & 63;
    const int rest = i >> 6;          // g*75 + t*3 + co
    const int g = rest / 75;
    const int tc = rest - 75 * g;
    const int t = tc / 3;
    const int co = tc - 3 * t;
    const int th = t / 5;
    const int tw = t - 5 * th;
    const int q = lane >> 4;
    const int pl = lane & 15;
    float v = 0.f;
    if (q < 3) {
      const int p = g * 16 + pl;
      const int ph = p >> 3;
      const int pw = p & 7;
      v = w_conv[(((8 * th + ph) * 40 + (8 * tw + pw)) * 3 + q) * 3 + co];
    }
    ws[WGOFF + i] = v;
  }
  if (i < 600) {
    const int c = i / 200;
    const int rem = i - 200 * c;
    float v = 0.f;
    if (rem < 192) {
      const int ci = rem >> 6;
      const int p = rem & 63;
      const int rh = p >> 3;
      const int rw = p & 7;
      if (rh < 5 && rw < 5) v = w_ct[(((4 - rh) * 5 + (4 - rw)) * 3 + ci) * 3 + c];
    }
    ws[WCTOFF + i] = v;
  }
  if (i < 4096) ((int*)ws)[CNTOFF + i] = 0;
}

__global__ __launch_bounds__(THREADS) void fista_split(
    float* __restrict__ ws,
    const float* __restrict__ x, const float* __restrict__ lam,
    const float* __restrict__ b_conv, const float* __restrict__ b_ct,
    float* __restrict__ out) {
  __shared__ __align__(16) float smem[SMEMF];
  const int tid = threadIdx.x;
  const int blk = blockIdx.x;
  const int n = blk & 63;         // image  (XCD colocation: n, n+64, n+128,
  const int g = blk >> 6;         //  n+192 share blk%8)
  const int lane = tid & 63;
  const int wid = tid >> 6;       // wave index (9 waves)
  const int q = lane >> 4;        // ci quadrant (3 = dead)
  const int pl = lane & 15;
  const int ylane = ((q < 3) ? q : 2) * 16 + pl;  // q=3 dupes q=2: broadcast
  // wave->row perm {0,4,2,3,8,5,6,7,1}: per-SIMD tap-row load balanced (10).
  const int oh = (wid == 0) ? 0 : (wid == 1) ? 4 : (wid == 4) ? 8
               : (wid == 8) ? 1 : wid;

  int* __restrict__ cnt = (int*)ws + CNTOFF + n * 64;
  const float lam_n = lam[n];
  const float bcv = b_conv[tid % 3];   // pre-pass bias (used when tid<243)
  const float bct0 = b_ct[0], bct1 = b_ct[1], bct2 = b_ct[2];

  // ---- stage LDS: zero all, scatter conv weights to [tap][lane][4],
  // copy Wct + x slice ----
  for (int i = tid; i < SMEMF; i += THREADS) smem[i] = 0.f;
  __syncthreads();
  for (int i = tid; i < 4800; i += THREADS) {
    const int lane_i = i & 63;
    const int tc = i >> 6;            // t*3 + co
    const int t_i = tc / 3;
    const int co_i = tc - 3 * t_i;
    smem[LWG + (t_i * 64 + lane_i) * 4 + co_i] = ws[WGOFF + g * 4800 + i];
  }
  for (int i = tid; i < 600; i += THREADS) smem[LWCT + i] = ws[WCTOFF + i];
  if (tid < 243) smem[LXS + tid] = x[n * 243 + tid];
  __syncthreads();

  // stage-2 ownership: thread t<486 owns elements e = 8t .. 8t+7
  const int idx3 = tid >> 1;
  const int cell = idx3 / 3;
  const int c = idx3 - 3 * cell;
  const int cb = 3 * cell;
  const int plb = (tid & 1) * 8;       // p_local base (0 or 8)
  const int pb = g * 16 + plb;         // global p base

  // ---- R33: y_last in PERSISTENT registers (thread-private; 8 VGPR).
  // Holds exactly the values the old LYL region held; init 0 == zeroed LDS.
  float yl[8];
#pragma unroll
  for (int j = 0; j < 8; ++j) yl[j] = 0.f;

  float t = 1.0f;
#pragma unroll 1
  for (int iter = 0; iter < ITERS; ++iter) {
    // ===== stage 1: partial a over this block's 16 phases; wave = oh ==========
    {
      f32x2 a01[9];                // [ow] = (co0, co1)
      float a2[9];                 // [ow] = co2
#pragma unroll
      for (int k = 0; k < 9; ++k) { a01[k].x = 0.f; a01[k].y = 0.f; a2[k] = 0.f; }

#pragma unroll
      for (int th = 0; th < 5; ++th) {
        const int r = oh + th - 2;          // input row
        if (r >= 0 && r <= 8) {
          f32x2 y2[9];                      // broadcast pairs {y,y}
#pragma unroll
          for (int wc = 0; wc < 9; ++wc) {
            const float yv = smem[LY + r * 432 + wc * 48 + ylane];
            y2[wc].x = yv; y2[wc].y = yv;
          }

#pragma unroll
          for (int tw = 0; tw < 5; ++tw) {
            const float4 wv =
                *(const float4*)&smem[LWG + ((th * 5 + tw) * 64 + lane) * 4];
            f32x2 w01; w01.x = wv.x; w01.y = wv.y;
#pragma unroll
            for (int ow = 0; ow < 9; ++ow) {
              const int col = ow + tw - 2;
              if (col >= 0 && col <= 8) {   // compile-time trim
                a01[ow] += y2[col] * w01;   // v_pk_fma_f32
                a2[ow]  += y2[col].x * wv.z;
              }
            }
          }
        }
      }

      // ---- reduce (R23-proven): 2 DPP stages -> 4-lane sums; masked
      // transpose write (stride 20, conflict-free); lanes<27 final sum;
      // ONE coalesced 27-lane atomic store ----
      float s4[27];
#pragma unroll
      for (int k = 0; k < 27; ++k) {
        const int ow = k / 3, co = k - 3 * ow;      // compile-time
        const float av = (co == 0) ? a01[ow].x : (co == 1) ? a01[ow].y : a2[ow];
        const float s1 = dpp_add<0x111>(av);        // row_shr:1
        s4[k] = dpp_add<0x112>(s1);                 // row_shr:2 -> 4-group sum
      }
      {
        float* Tw = &smem[LT + wid * 540];
        if ((lane & 3) == 3) {
          const int m = lane >> 2;                  // 0..15
#pragma unroll
          for (int k = 0; k < 27; ++k) Tw[k * 20 + m] = s4[k];
        }
        asm volatile("s_waitcnt lgkmcnt(0)" ::: "memory");
        if (lane < 27) {
          const float4* Tr = (const float4*)&Tw[lane * 20];
          const float4 p0 = Tr[0];
          const float4 p1 = Tr[1];
          const float4 p2 = Tr[2];
          const float4 p3 = Tr[3];
          const float s01 = (p0.x + p0.y) + (p0.z + p0.w);
          const float s23 = (p1.x + p1.y) + (p1.z + p1.w);
          const float s45 = (p2.x + p2.y) + (p2.z + p2.w);
          const float s67 = (p3.x + p3.y) + (p3.z + p3.w);
          const float s = (s01 + s23) + (s45 + s67);
          float* ap = ws + APOFF + ((((iter & 1) * 64 + n) * 4 + g) * 243)
                      + oh * 27 + lane;
          __hip_atomic_store(ap, s, __ATOMIC_RELAXED, __HIP_MEMORY_SCOPE_AGENT);
        }
      }
    }

    // ===== pre-gate prefetch: stage-2 operands -> regs (latency hides
    // under drain + spin; thread-owned slots only). No ylast prefetch. =====
    float4 py0 = {}, py1 = {};
    float4 w0a = {}, w0b = {}, w1a = {}, w1b = {}, w2a = {}, w2b = {};
    if (tid < 486) {
      float4* lyv = (float4*)&smem[LY];
      py0 = lyv[2 * tid];  py1 = lyv[2 * tid + 1];
      w0a = *(const float4*)&smem[LWCT + c * 200 +   0 + pb];
      w0b = *(const float4*)&smem[LWCT + c * 200 +   4 + pb];
      w1a = *(const float4*)&smem[LWCT + c * 200 +  64 + pb];
      w1b = *(const float4*)&smem[LWCT + c * 200 +  68 + pb];
      w2a = *(const float4*)&smem[LWCT + c * 200 + 128 + pb];
      w2b = *(const float4*)&smem[LWCT + c * 200 + 132 + pb];
    }

    // ===== centralized barrier (proven): one spinner, rest at s_barrier =====
    __syncthreads();               // compiler drains vmcnt: Ap stores acked at L3
    if (tid == 0) {
      __hip_atomic_fetch_add(cnt, 1, __ATOMIC_RELAXED, __HIP_MEMORY_SCOPE_AGENT);
      const int target = 4 * (iter + 1);
      while (__hip_atomic_load(cnt, __ATOMIC_RELAXED, __HIP_MEMORY_SCOPE_AGENT)
             < target)
        __builtin_amdgcn_s_sleep(1);
    }
    __syncthreads();

    // ===== pre-pass: r = x - (sum_g Ap + b_conv) -> LDS =====
    if (tid < 243) {
      const float* ap = ws + APOFF + ((iter & 1) * 64 + n) * 972;
      const float a0 = __hip_atomic_load(ap + tid, __ATOMIC_RELAXED,
                                         __HIP_MEMORY_SCOPE_AGENT);
      const float a1 = __hip_atomic_load(ap + 243 + tid, __ATOMIC_RELAXED,
                                         __HIP_MEMORY_SCOPE_AGENT);
      const float a2v = __hip_atomic_load(ap + 486 + tid, __ATOMIC_RELAXED,
                                          __HIP_MEMORY_SCOPE_AGENT);
      const float a3 = __hip_atomic_load(ap + 729 + tid, __ATOMIC_RELAXED,
                                         __HIP_MEMORY_SCOPE_AGENT);
      smem[LA + tid] = smem[LXS + tid] - (a0 + a1 + a2v + a3 + bcv);
    }
    __syncthreads();

    const float tn = (1.0f + sqrtf(1.0f + 4.0f * t * t)) * 0.5f;
    const float beta = (t - 1.0f) / tn;    // beta_0 = 0
    t = tn;

    // ===== stage 2: 8 elements/thread; y prefetched, y_last in regs =====
    const bool lastit = (iter == ITERS - 1);
    if (tid < 486) {
      const float r0  = smem[LA + cb + 0];
      const float r1  = smem[LA + cb + 1];
      const float r2v = smem[LA + cb + 2];
      const float bct = (c == 0) ? bct0 : ((c == 1) ? bct1 : bct2);

      const float wct0[8] = {w0a.x, w0a.y, w0a.z, w0a.w, w0b.x, w0b.y, w0b.z, w0b.w};
      const float wct1[8] = {w1a.x, w1a.y, w1a.z, w1a.w, w1b.x, w1b.y, w1b.z, w1b.w};
      const float wct2[8] = {w2a.x, w2a.y, w2a.z, w2a.w, w2b.x, w2b.y, w2b.z, w2b.w};
      const float yv[8]   = {py0.x, py0.y, py0.z, py0.w, py1.x, py1.y, py1.z, py1.w};
      float yn[8];
#pragma unroll
      for (int j = 0; j < 8; ++j) {
        const float re = bct + r0 * wct0[j] + r1 * wct1[j] + r2v * wct2[j];
        const float wvv = yv[j] - re;
        yn[j] = fmaxf(wvv - lam_n, 0.f) - fmaxf(-wvv - lam_n, 0.f);
      }

      if (!lastit) {
        float4 m0, m1;
        m0.x = yn[0] + beta * (yn[0] - yl[0]);
        m0.y = yn[1] + beta * (yn[1] - yl[1]);
        m0.z = yn[2] + beta * (yn[2] - yl[2]);
        m0.w = yn[3] + beta * (yn[3] - yl[3]);
        m1.x = yn[4] + beta * (yn[4] - yl[4]);
        m1.y = yn[5] + beta * (yn[5] - yl[5]);
        m1.z = yn[6] + beta * (yn[6] - yl[6]);
        m1.w = yn[7] + beta * (yn[7] - yl[7]);
#pragma unroll
        for (int j = 0; j < 8; ++j) yl[j] = yn[j];
        float4* lyv = (float4*)&smem[LY];
        lyv[2 * tid] = m0; lyv[2 * tid + 1] = m1;
      } else {
        const int part = pb >> 3;           // p>>3 constant over j
        const int qh = cell / 9;
        const int qw = cell - 9 * qh;
        const int ih = 8 * qh + part;
        float* op = out + ((n * 72 + ih) * 72 + 8 * qw) * 3 + c;
#pragma unroll
        for (int j = 0; j < 8; ++j) op[3 * j] = yn[j];
      }
    }
    __syncthreads();
  }
}

extern "C" void kernel_launch(void* const* d_in, const int* in_sizes, int n_in,
                              void* d_out, int out_size, void* d_ws, size_t ws_size,
                              hipStream_t stream) {
  const float* x      = (const float*)d_in[0];
  const float* lam    = (const float*)d_in[1];
  const float* w_conv = (const float*)d_in[2];
  const float* b_conv = (const float*)d_in[3];
  const float* w_ct   = (const float*)d_in[4];
  const float* b_ct   = (const float*)d_in[5];
  float* out = (float*)d_out;
  float* ws  = (float*)d_ws;  // needs ~594 KB

  hipLaunchKernelGGL(k0_init, dim3(80), dim3(256), 0, stream, w_conv, w_ct, ws);
  hipLaunchKernelGGL(fista_split, dim3(256), dim3(THREADS), 0, stream,
                     ws, x, lam, b_conv, b_ct, out);
}